// Round 10
// baseline (426.625 us; speedup 1.0000x reference)
//
#include <hip/hip_runtime.h>
#include <math.h>

typedef _Float16 f16;
typedef _Float16 half8 __attribute__((ext_vector_type(8)));
typedef _Float16 half4 __attribute__((ext_vector_type(4)));
typedef float float4v __attribute__((ext_vector_type(4)));
typedef int int4v __attribute__((ext_vector_type(4)));

#define MFMA16(a, b, c) __builtin_amdgcn_mfma_f32_16x16x32_f16((a), (b), (c), 0, 0, 0)

// problem: B=4096 L=32 V=50000 D=300 H=6 HD=50 ; K padded to 320
// Fragment-swizzled layout: element (n, k) of a [Nt*16][320] matrix lives at
//   F[((n>>4)*10 + (k>>5))*512 + (((k>>3)&3)*16 + (n&15))*8 + (k&7)]

// ---------------- ws layout (bytes) ----------------
#define WQKV_OFF 0u          // f16 frag-swizzled [64 ntiles] (q*rs | k | v rows, pads 0)
#define BQKV_OFF 655360u     // f32 [1024]
#define WO_OFF   659456u     // f16 frag-swizzled [20 ntiles] Wo
#define WVA_OFF  864256u     // f16 frag-swizzled [20 ntiles] Va@Wo
#define BVA_OFF  1069056u    // f32 [320]  Va@bo+ba (pads 0)
#define CBAR_OFF 1070336u    // f16 [4096][320] row-major

__device__ __forceinline__ float fast_tanh(float x) {
    float e = __expf(2.f * x);
    return 1.f - 2.f / (e + 1.f);
}

// ------- repack_all: vectorized repack1 | 4x-parallel repack2 | repack3 ---
__global__ __launch_bounds__(256) void repack_all(
    const float* __restrict__ Wq, const float* __restrict__ Wk,
    const float* __restrict__ Wv, const float* __restrict__ Wo,
    const float* __restrict__ bq, const float* __restrict__ bk,
    const float* __restrict__ bv, const float* __restrict__ Va,
    const float* __restrict__ bo, const float* __restrict__ ba,
    f16* __restrict__ wqkvF, f16* __restrict__ wo16F, float* __restrict__ bqkv,
    f16* __restrict__ wvaF, float* __restrict__ bva) {
    __shared__ float4v red[4][64];
    const int bid = blockIdx.x, tid = threadIdx.x;
    const float rs = 0.14142135623730951f;  // 1/sqrt(50)
    const float4v vz = {0.f, 0.f, 0.f, 0.f};
    if (bid < 214) {
        int s = bid * 256 + tid;
        if (s < 40960) {  // wqkvF: 40960 half8 slots
            int a = s * 8;
            int ntile = a / 5120, rem = a - ntile * 5120;
            int ks = rem / 512, r2 = rem - ks * 512;
            int lane = r2 >> 3;
            int n = ntile * 16 + (lane & 15);
            int k = ks * 32 + (lane >> 4) * 8;
            int g = n / 320, r = n - g * 320;
            half8 h;
#pragma unroll
            for (int j = 0; j < 8; ++j) h[j] = (f16)0.f;
            if (g < 3 && r < 300) {
                const float* W = (g == 0) ? Wq : (g == 1) ? Wk : Wv;
                float sc = (g == 0) ? rs : 1.f;
                if (k + 8 <= 300) {
                    float4v v0 = *(const float4v*)&W[r * 300 + k];
                    float4v v1 = *(const float4v*)&W[r * 300 + k + 4];
#pragma unroll
                    for (int j = 0; j < 4; ++j) {
                        h[j] = (f16)(v0[j] * sc);
                        h[4 + j] = (f16)(v1[j] * sc);
                    }
                } else {
#pragma unroll
                    for (int j = 0; j < 8; ++j) {
                        int kk = k + j;
                        if (kk < 300) h[j] = (f16)(W[r * 300 + kk] * sc);
                    }
                }
            }
            *(half8*)&wqkvF[a] = h;
        } else if (s < 53760) {  // wo16F: 12800 half8 slots
            int a = (s - 40960) * 8;
            int ntile = a / 5120, rem = a - ntile * 5120;
            int ks = rem / 512, r2 = rem - ks * 512;
            int lane = r2 >> 3;
            int n = ntile * 16 + (lane & 15);
            int k = ks * 32 + (lane >> 4) * 8;
            half8 h;
#pragma unroll
            for (int j = 0; j < 8; ++j) h[j] = (f16)0.f;
            if (n < 300) {
                if (k + 8 <= 300) {
                    float4v v0 = *(const float4v*)&Wo[n * 300 + k];
                    float4v v1 = *(const float4v*)&Wo[n * 300 + k + 4];
#pragma unroll
                    for (int j = 0; j < 4; ++j) {
                        h[j] = (f16)v0[j];
                        h[4 + j] = (f16)v1[j];
                    }
                } else {
#pragma unroll
                    for (int j = 0; j < 8; ++j) {
                        int kk = k + j;
                        if (kk < 300) h[j] = (f16)Wo[n * 300 + kk];
                    }
                }
            }
            *(half8*)&wo16F[a] = h;
        } else if (s < 54784) {  // bqkv [1024]
            int n = s - 53760;
            int g = n / 320, r = n - g * 320;
            float v = 0.f;
            if (r < 300) {
                if (g == 0) v = bq[r] * rs;
                else if (g == 1) v = bk[r];
                else if (g == 2) v = bv[r];
            }
            bqkv[n] = v;
        }
    } else if (bid < 614) {  // ---- repack2: Wva = Va @ Wo, 400 blocks ----
        int bt = bid - 214;
        int mt = bt / 20, nt = bt - mt * 20;
        int w = tid >> 6, lane = tid & 63;
        int lr = lane & 15, quad = lane >> 4;
        int m = mt * 16 + lr;   // Wva row
        int nn = nt * 16 + lr;  // Wva col (= Wo output dim)
        float4v acc = vz;
        int ks0 = (w < 2) ? w * 3 : 6 + (w - 2) * 2;
        int ksn = (w < 2) ? 3 : 2;
        for (int kk = 0; kk < ksn; ++kk) {
            int c = (ks0 + kk) * 32 + quad * 8;
            half8 af, bf;
#pragma unroll
            for (int j = 0; j < 8; ++j) {
                int cc = c + j;
                af[j] = (f16)((m < 300 && cc < 300) ? Va[m * 300 + cc] : 0.f);
                bf[j] = (f16)((nn < 300 && cc < 300) ? Wo[cc * 300 + nn] : 0.f);
            }
            acc = MFMA16(af, bf, acc);
        }
        red[w][lane] = acc;
        __syncthreads();
        if (w == 0) {
            float4v s = red[0][lane] + red[1][lane] + red[2][lane] + red[3][lane];
#pragma unroll
            for (int r = 0; r < 4; ++r) {
                int row = mt * 16 + quad * 4 + r;  // Wva row index (n of va GEMM)
                int col = nt * 16 + lr;            // Wva col index (k of va GEMM)
                int addr = ((row >> 4) * 10 + (col >> 5)) * 512 +
                           (((col >> 3) & 3) * 16 + (row & 15)) * 8 + (col & 7);
                wvaF[addr] = (f16)s[r];
            }
        }
    } else {  // ---- repack3: bva = Va @ bo + ba, 320 rows ----
        int j = (bid - 614) * 4 + (tid >> 6);  // 0..319
        int lane = tid & 63;
        float s = 0.f;
        if (j < 300) {
            for (int k = lane; k < 300; k += 64) s += Va[j * 300 + k] * bo[k];
        }
#pragma unroll
        for (int off = 1; off < 64; off <<= 1) s += __shfl_xor(s, off, 64);
        if (lane == 0) bva[j] = (j < 300) ? s + ba[j] : 0.f;
    }
}

// P4 helper: NT n-tiles x BOTH m-tiles per wave. All indices compile-time
// after unroll (no conditional arrays -> no scratch spill).
template <int NT>
__device__ __forceinline__ void p4_work(int tb, const f16* scratch,
                                        const f16* __restrict__ wvaF,
                                        const float* __restrict__ bva,
                                        const float* __restrict__ qw,
                                        float* aL, int lane, int lr, int quad) {
    const float4v vz = {0.f, 0.f, 0.f, 0.f};
    const f16* vp = wvaF + tb * 5120 + lane * 8;
    float pbva[NT], pqw[NT];
#pragma unroll
    for (int i = 0; i < NT; ++i) {
        int n = (tb + i) * 16 + lr;
        pbva[i] = bva[n];
        pqw[i] = (n < 300) ? qw[n] : 0.f;
    }
    float4v vacc[2][NT];
#pragma unroll
    for (int mt = 0; mt < 2; ++mt)
#pragma unroll
        for (int i = 0; i < NT; ++i) vacc[mt][i] = vz;
#pragma unroll
    for (int ks = 0; ks < 10; ++ks) {
        half8 a0 = *(const half8*)&scratch[lr * 328 + ks * 32 + quad * 8];
        half8 a1 = *(const half8*)&scratch[(16 + lr) * 328 + ks * 32 + quad * 8];
#pragma unroll
        for (int i = 0; i < NT; ++i) {
            half8 bf = *(const half8*)(vp + i * 5120 + ks * 512);
            vacc[0][i] = MFMA16(a0, bf, vacc[0][i]);
            vacc[1][i] = MFMA16(a1, bf, vacc[1][i]);
        }
    }
    float ps[2][4] = {{0.f, 0.f, 0.f, 0.f}, {0.f, 0.f, 0.f, 0.f}};
#pragma unroll
    for (int i = 0; i < NT; ++i)
#pragma unroll
        for (int mt = 0; mt < 2; ++mt)
#pragma unroll
            for (int r = 0; r < 4; ++r)
                ps[mt][r] += fast_tanh(vacc[mt][i][r] + pbva[i]) * pqw[i];
#pragma unroll
    for (int mt = 0; mt < 2; ++mt)
#pragma unroll
        for (int r = 0; r < 4; ++r)
#pragma unroll
            for (int off = 1; off < 16; off <<= 1)
                ps[mt][r] += __shfl_xor(ps[mt][r], off, 64);
    if (lr == 0) {
#pragma unroll
        for (int mt = 0; mt < 2; ++mt)
#pragma unroll
            for (int r = 0; r < 4; ++r)
                atomicAdd(&aL[mt * 16 + quad * 4 + r], ps[mt][r]);
    }
}

// P1 helper: NJ consecutive tiles from tb, straight-line k-loop; the FP32
// accumulators stay branch-LOCAL — output is packed bias-added f16 (pk),
// so only 32 VGPRs of state cross the wave-specialization join (no spill).
template <int NJ>
__device__ __forceinline__ void p1_compute(int tb, const f16* xA,
                                           const f16* __restrict__ wqkvF,
                                           const float* bb, half4 (*pk)[8],
                                           int lane) {
    const float4v vz = {0.f, 0.f, 0.f, 0.f};
    const f16* bp = wqkvF + tb * 5120 + lane * 8;
    float4v acc[2][NJ];
#pragma unroll
    for (int mt = 0; mt < 2; ++mt)
#pragma unroll
        for (int j = 0; j < NJ; ++j) acc[mt][j] = vz;
#pragma unroll
    for (int ks = 0; ks < 10; ++ks) {
        half8 a0 = *(const half8*)&xA[(ks * 64 + lane) * 8];
        half8 a1 = *(const half8*)&xA[((10 + ks) * 64 + lane) * 8];
#pragma unroll
        for (int j = 0; j < NJ; ++j) {
            half8 bf = *(const half8*)(bp + j * 5120 + ks * 512);
            acc[0][j] = MFMA16(a0, bf, acc[0][j]);
            acc[1][j] = MFMA16(a1, bf, acc[1][j]);
        }
    }
#pragma unroll
    for (int mt = 0; mt < 2; ++mt) {
#pragma unroll
        for (int j = 0; j < NJ; ++j) {
            half4 p;
#pragma unroll
            for (int r = 0; r < 4; ++r) p[r] = (f16)(acc[mt][j][r] + bb[j]);
            pk[mt][j] = p;
        }
#pragma unroll
        for (int j = NJ; j < 8; ++j) {
            half4 p;
#pragma unroll
            for (int r = 0; r < 4; ++r) p[r] = (f16)0.f;
            pk[mt][j] = p;
        }
    }
}

// ---- fused gather + QKV GEMM + attention + va + softmax + pool ----
// 1 item/block. LDS: qL/kL [6*32][72], vT [6*64][32] = 80,064 B -> 2 blocks/CU.
// P1 wave-specialized with branch-local accumulators (packed pk crosses join).
__global__ __launch_bounds__(512, 4) void qkvattn_kernel(
    const int* __restrict__ title, const float* __restrict__ emb,
    const float* __restrict__ pos,
    const f16* __restrict__ wqkvF, const float* __restrict__ bqkv,
    const f16* __restrict__ wvaF, const float* __restrict__ bva,
    const float* __restrict__ qw, f16* __restrict__ cbar) {
    __shared__ __align__(16) f16 qL[6 * 32 * 72];
    __shared__ __align__(16) f16 kL[6 * 32 * 72];
    __shared__ __align__(16) f16 vT[6 * 64 * 32];  // first 20480 B alias xA staging
    __shared__ float aL[32];
    const int ib = blockIdx.x, tid = threadIdx.x;
    const int w = tid >> 6, lane = tid & 63, lr = lane & 15, quad = lane >> 4;
    const float4v vz = {0.f, 0.f, 0.f, 0.f};
    const int4v z4 = {0, 0, 0, 0};
    f16* xA = vT;  // [20 fragblks][64 lanes][8] f16 = 20480 B

    // --- P0: gather x = emb[title]+pos into LDS frag layout (aliases vT) ---
    for (int u = tid; u < 1280; u += 512) {
        int fragblk = u >> 6, lu = u & 63;
        int mt = fragblk / 10, ks = fragblk - mt * 10;
        int row = mt * 16 + (lu & 15);        // l index 0..31
        int col = ks * 32 + (lu >> 4) * 8;
        int t = title[ib * 32 + row];
        half8 h;
        if (col + 8 <= 300) {
            float4v e0 = *(const float4v*)&emb[t * 300 + col];
            float4v e1 = *(const float4v*)&emb[t * 300 + col + 4];
            float4v p0 = *(const float4v*)&pos[row * 300 + col];
            float4v p1 = *(const float4v*)&pos[row * 300 + col + 4];
#pragma unroll
            for (int j = 0; j < 4; ++j) {
                h[j] = (f16)(e0[j] + p0[j]);
                h[4 + j] = (f16)(e1[j] + p1[j]);
            }
        } else {
#pragma unroll
            for (int j = 0; j < 8; ++j) {
                int cc = col + j;
                h[j] = (f16)((cc < 300) ? emb[t * 300 + cc] + pos[row * 300 + cc] : 0.f);
            }
        }
        *(half8*)&xA[u * 8] = h;
    }
    // qL/kL pad zeroing (cols 50..63) — disjoint from P1 epilogue writes
    for (int i = tid; i < 1344; i += 512) {  // 192 hrows x 7 dwords
        int hrow = i / 7, c = i - hrow * 7;
        ((int*)&qL[hrow * 72 + 50])[c] = 0;
        ((int*)&kL[hrow * 72 + 50])[c] = 0;
    }
    if (tid < 32) aL[tid] = 0.f;
    // hoist bqkv bias loads (global, independent of LDS)
    float bb[8];
#pragma unroll
    for (int j = 0; j < 8; ++j) bb[j] = bqkv[(w * 8 + j) * 16 + lr];
    __syncthreads();  // xA visible

    // --- Phase 1: QKV GEMM, wave-specialized; result packed in pk ---
    half4 pk[2][8];
    if (w < 7) p1_compute<8>(w * 8, xA, wqkvF, bb, pk, lane);
    else       p1_compute<3>(56, xA, wqkvF, bb, pk, lane);  // 59..63 pure pad
    __syncthreads();  // all xA reads done; vT may now be overwritten

    // vT pad zeroing (rows d=50..63 per head)
    for (int i = tid; i < 336; i += 512) {
        int t = i >> 2, c4 = i & 3;
        int h = t / 14, d = 50 + (t - (t / 14) * 14);
        ((int4v*)&vT[(h * 64 + d) * 32])[c4] = z4;
    }
    // epilogue: scatter pk (q/k/v) into LDS (wi is wave-uniform per j: 8 | 20)
#pragma unroll
    for (int j = 0; j < 8; ++j) {
        int tile = w * 8 + j;
        int wi = tile / 20;
        int n = tile * 16 + lr;
        int cc = n - wi * 320;
        if (wi < 3 && cc < 300) {
            int h = cc / 50, d = cc - h * 50;
            if (wi == 2) {  // v: packed b64 write, XOR-swizzled on byte bits 4-5
#pragma unroll
                for (int mt = 0; mt < 2; ++mt) {
                    int row0 = mt * 16 + quad * 4;
                    int idx = (h * 64 + d) * 32 + row0;
                    int byt = (idx * 2) ^ (((d >> 2) & 3) << 4);
                    *(half4*)((char*)vT + byt) = pk[mt][j];
                }
            } else {
                f16* dst = (wi == 0) ? qL : kL;
#pragma unroll
                for (int mt = 0; mt < 2; ++mt)
#pragma unroll
                    for (int r = 0; r < 4; ++r) {
                        int row = mt * 16 + quad * 4 + r;
                        dst[(h * 32 + row) * 72 + d] = pk[mt][j][r];
                    }
            }
        }
    }
    __syncthreads();

    // --- Phase 2: wave hh (<6) computes scores + softmax -> P (aliases qL) ---
    const int hh = w;
    if (w < 6) {
        float4v s00 = vz, s01 = vz, s10 = vz, s11 = vz;
#pragma unroll
        for (int ks = 0; ks < 2; ++ks) {
            int c = ks * 32 + quad * 8;
            half8 aq0 = *(const half8*)&qL[(hh * 32 + lr) * 72 + c];
            half8 aq1 = *(const half8*)&qL[(hh * 32 + 16 + lr) * 72 + c];
            half8 bk0 = *(const half8*)&kL[(hh * 32 + lr) * 72 + c];
            half8 bk1 = *(const half8*)&kL[(hh * 32 + 16 + lr) * 72 + c];
            s00 = MFMA16(aq0, bk0, s00);
            s01 = MFMA16(aq0, bk1, s01);
            s10 = MFMA16(aq1, bk0, s10);
            s11 = MFMA16(aq1, bk1, s11);
        }
        f16* ph = qL + hh * 32 * 72;
#pragma unroll
        for (int mt = 0; mt < 2; ++mt) {
            float4v sv0 = mt ? s10 : s00;
            float4v sv1 = mt ? s11 : s01;
#pragma unroll
            for (int r = 0; r < 4; ++r) {
                float v0 = sv0[r], v1 = sv1[r];
                float m = fmaxf(v0, v1);
#pragma unroll
                for (int off = 1; off < 16; off <<= 1) m = fmaxf(m, __shfl_xor(m, off, 64));
                float e0 = __expf(v0 - m), e1 = __expf(v1 - m);
                float ss = e0 + e1;
#pragma unroll
                for (int off = 1; off < 16; off <<= 1) ss += __shfl_xor(ss, off, 64);
                float inv = 1.0f / ss;
                int row = mt * 16 + quad * 4 + r;
                ph[row * 40 + lr] = (f16)(e0 * inv);
                ph[row * 40 + 16 + lr] = (f16)(e1 * inv);
            }
        }
    }
    __syncthreads();

    // --- Phase 3: ctx = P @ V -> row-major scratch (reuses kL, [32][328]) ---
    f16* scratch = kL;
    for (int i = tid; i < 32 * 28; i += 512) {  // zero pad cols 300..327
        int row = i / 28, cc = 300 + (i - row * 28);
        scratch[row * 328 + cc] = (f16)0.f;
    }
    if (w < 6) {
        int h = hh;
        f16* ph = qL + hh * 32 * 72;
        half8 aw0 = *(const half8*)&ph[lr * 40 + quad * 8];
        half8 aw1 = *(const half8*)&ph[(16 + lr) * 40 + quad * 8];
        float4v c0[4], c1[4];
#pragma unroll
        for (int nt = 0; nt < 4; ++nt) { c0[nt] = vz; c1[nt] = vz; }
#pragma unroll
        for (int nt = 0; nt < 4; ++nt) {
            int rIdx = nt * 16 + lr;
            int idx = (hh * 64 + rIdx) * 32 + quad * 8;
            int byt = (idx * 2) ^ (((rIdx >> 2) & 3) << 4);
            half8 bvf = *(const half8*)((const char*)vT + byt);
            c0[nt] = MFMA16(aw0, bvf, c0[nt]);
            c1[nt] = MFMA16(aw1, bvf, c1[nt]);
        }
#pragma unroll
        for (int mt = 0; mt < 2; ++mt)
#pragma unroll
            for (int nt = 0; nt < 4; ++nt)
#pragma unroll
                for (int r = 0; r < 4; ++r) {
                    int d = nt * 16 + lr;
                    if (d < 50) {
                        int row = mt * 16 + quad * 4 + r;
                        float4v cv = mt ? c1[nt] : c0[nt];
                        scratch[row * 328 + h * 50 + d] = (f16)cv[r];
                    }
                }
    }
    __syncthreads();

    // --- Phase 4: va GEMM (deduped): wave w owns disjoint n-tiles, both m-tiles ---
    if (w < 4) p4_work<3>(w * 3, scratch, wvaF, bva, qw, aL, lane, lr, quad);
    else       p4_work<2>(12 + (w - 4) * 2, scratch, wvaF, bva, qw, aL, lane, lr, quad);
    __syncthreads();

    // --- Phase 5+6 fused: redundant 32-softmax per wave, alpha via shfl ---
    {
        float av = aL[lane & 31];
        float m5 = av;
#pragma unroll
        for (int off = 1; off < 32; off <<= 1) m5 = fmaxf(m5, __shfl_xor(m5, off, 32));
        float e5 = __expf(av - m5);
        float ss5 = e5;
#pragma unroll
        for (int off = 1; off < 32; off <<= 1) ss5 += __shfl_xor(ss5, off, 32);
        float al = e5 / ss5;  // lane (l&31) holds alpha[l&31]
        if (tid < 320) {
            int d = tid;
            float acc6 = 0.f;
#pragma unroll
            for (int l = 0; l < 32; ++l)
                acc6 += __shfl(al, l, 32) * (float)scratch[l * 328 + d];
            cbar[ib * 320 + d] = (f16)acc6;
        }
    }
}

// ------- out = cbar @ Wo^T + bo, f32 [4096][300]; 256 blocks x M=16 -------
__global__ __launch_bounds__(512) void out_kernel(
    const f16* __restrict__ cbar, const f16* __restrict__ wo16F,
    const float* __restrict__ bo, float* __restrict__ out) {
    __shared__ __align__(16) f16 cA[16 * 328];
    const int mb = blockIdx.x, tid = threadIdx.x;  // 256 blocks, M=16
    const int w = tid >> 6, lane = tid & 63, lr = lane & 15, quad = lane >> 4;
    for (int i = tid; i < 640; i += 512) {
        int row = i / 40, g = i - row * 40;
        *(half8*)&cA[row * 328 + g * 8] = *(const half8*)&cbar[(mb * 16 + row) * 320 + g * 8];
    }
    __syncthreads();
    const float4v vz = {0.f, 0.f, 0.f, 0.f};
    for (int t = w; t < 19; t += 8) {
        float4v acc = vz;
#pragma unroll
        for (int ks = 0; ks < 10; ++ks) {
            half8 a = *(const half8*)&cA[lr * 328 + ks * 32 + quad * 8];
            half8 bf = *(const half8*)&wo16F[((t * 10 + ks) * 64 + lane) * 8];
            acc = MFMA16(a, bf, acc);
        }
        int n = t * 16 + lr;
        if (n < 300) {
            float bb = bo[n];
#pragma unroll
            for (int r = 0; r < 4; ++r)
                out[(mb * 16 + quad * 4 + r) * 300 + n] = acc[r] + bb;
        }
    }
}

// ---------------- host launcher ----------------
extern "C" void kernel_launch(void* const* d_in, const int* in_sizes, int n_in,
                              void* d_out, int out_size, void* d_ws, size_t ws_size,
                              hipStream_t stream) {
    const int* title = (const int*)d_in[0];
    const float* emb = (const float*)d_in[1];
    const float* pos = (const float*)d_in[2];
    const float* Wq = (const float*)d_in[3];
    const float* bq = (const float*)d_in[4];
    const float* Wk = (const float*)d_in[5];
    const float* bk = (const float*)d_in[6];
    const float* Wv = (const float*)d_in[7];
    const float* bv = (const float*)d_in[8];
    const float* Wo = (const float*)d_in[9];
    const float* bo = (const float*)d_in[10];
    const float* Va = (const float*)d_in[11];
    const float* ba = (const float*)d_in[12];
    const float* qw = (const float*)d_in[13];
    char* ws = (char*)d_ws;
    float* out = (float*)d_out;

    f16* wqkvF = (f16*)(ws + WQKV_OFF);
    float* bqkv = (float*)(ws + BQKV_OFF);
    f16* wo16F = (f16*)(ws + WO_OFF);
    f16* wvaF = (f16*)(ws + WVA_OFF);
    float* bva = (float*)(ws + BVA_OFF);
    f16* cbar = (f16*)(ws + CBAR_OFF);

    repack_all<<<694, 256, 0, stream>>>(Wq, Wk, Wv, Wo, bq, bk, bv, Va, bo, ba,
                                        wqkvF, wo16F, bqkv, wvaF, bva);
    qkvattn_kernel<<<4096, 512, 0, stream>>>(title, emb, pos, wqkvF, bqkv, wvaF, bva,
                                             qw, cbar);
    out_kernel<<<256, 512, 0, stream>>>(cbar, wo16F, bo, out);
}

// Round 11
// 390.192 us; speedup vs baseline: 1.0934x; 1.0934x over previous
//
#include <hip/hip_runtime.h>
#include <math.h>

typedef _Float16 f16;
typedef _Float16 half8 __attribute__((ext_vector_type(8)));
typedef _Float16 half4 __attribute__((ext_vector_type(4)));
typedef float float4v __attribute__((ext_vector_type(4)));
typedef int int4v __attribute__((ext_vector_type(4)));

#define MFMA16(a, b, c) __builtin_amdgcn_mfma_f32_16x16x32_f16((a), (b), (c), 0, 0, 0)

// problem: B=4096 L=32 V=50000 D=300 H=6 HD=50 ; K padded to 320
// Fragment-swizzled layout: element (n, k) of a [Nt*16][320] matrix lives at
//   F[((n>>4)*10 + (k>>5))*512 + (((k>>3)&3)*16 + (n&15))*8 + (k&7)]

// ---------------- ws layout (bytes) ----------------
#define WQKV_OFF 0u          // f16 frag-swizzled [64 ntiles] (q*rs | k | v rows, pads 0)
#define BQKV_OFF 655360u     // f32 [1024]
#define WO_OFF   659456u     // f16 frag-swizzled [20 ntiles] Wo
#define WVA_OFF  864256u     // f16 frag-swizzled [20 ntiles] Va@Wo
#define BVA_OFF  1069056u    // f32 [320]  Va@bo+ba (pads 0)
#define CBAR_OFF 1070336u    // f16 [4096][320] row-major

__device__ __forceinline__ float fast_tanh(float x) {
    float e = __expf(2.f * x);
    return 1.f - 2.f / (e + 1.f);
}

// ------- repack_all: vectorized repack1 | 4x-parallel repack2 | repack3 ---
__global__ __launch_bounds__(256) void repack_all(
    const float* __restrict__ Wq, const float* __restrict__ Wk,
    const float* __restrict__ Wv, const float* __restrict__ Wo,
    const float* __restrict__ bq, const float* __restrict__ bk,
    const float* __restrict__ bv, const float* __restrict__ Va,
    const float* __restrict__ bo, const float* __restrict__ ba,
    f16* __restrict__ wqkvF, f16* __restrict__ wo16F, float* __restrict__ bqkv,
    f16* __restrict__ wvaF, float* __restrict__ bva) {
    __shared__ float4v red[4][64];
    const int bid = blockIdx.x, tid = threadIdx.x;
    const float rs = 0.14142135623730951f;  // 1/sqrt(50)
    const float4v vz = {0.f, 0.f, 0.f, 0.f};
    if (bid < 214) {
        int s = bid * 256 + tid;
        if (s < 40960) {  // wqkvF: 40960 half8 slots
            int a = s * 8;
            int ntile = a / 5120, rem = a - ntile * 5120;
            int ks = rem / 512, r2 = rem - ks * 512;
            int lane = r2 >> 3;
            int n = ntile * 16 + (lane & 15);
            int k = ks * 32 + (lane >> 4) * 8;
            int g = n / 320, r = n - g * 320;
            half8 h;
#pragma unroll
            for (int j = 0; j < 8; ++j) h[j] = (f16)0.f;
            if (g < 3 && r < 300) {
                const float* W = (g == 0) ? Wq : (g == 1) ? Wk : Wv;
                float sc = (g == 0) ? rs : 1.f;
                if (k + 8 <= 300) {
                    float4v v0 = *(const float4v*)&W[r * 300 + k];
                    float4v v1 = *(const float4v*)&W[r * 300 + k + 4];
#pragma unroll
                    for (int j = 0; j < 4; ++j) {
                        h[j] = (f16)(v0[j] * sc);
                        h[4 + j] = (f16)(v1[j] * sc);
                    }
                } else {
#pragma unroll
                    for (int j = 0; j < 8; ++j) {
                        int kk = k + j;
                        if (kk < 300) h[j] = (f16)(W[r * 300 + kk] * sc);
                    }
                }
            }
            *(half8*)&wqkvF[a] = h;
        } else if (s < 53760) {  // wo16F: 12800 half8 slots
            int a = (s - 40960) * 8;
            int ntile = a / 5120, rem = a - ntile * 5120;
            int ks = rem / 512, r2 = rem - ks * 512;
            int lane = r2 >> 3;
            int n = ntile * 16 + (lane & 15);
            int k = ks * 32 + (lane >> 4) * 8;
            half8 h;
#pragma unroll
            for (int j = 0; j < 8; ++j) h[j] = (f16)0.f;
            if (n < 300) {
                if (k + 8 <= 300) {
                    float4v v0 = *(const float4v*)&Wo[n * 300 + k];
                    float4v v1 = *(const float4v*)&Wo[n * 300 + k + 4];
#pragma unroll
                    for (int j = 0; j < 4; ++j) {
                        h[j] = (f16)v0[j];
                        h[4 + j] = (f16)v1[j];
                    }
                } else {
#pragma unroll
                    for (int j = 0; j < 8; ++j) {
                        int kk = k + j;
                        if (kk < 300) h[j] = (f16)Wo[n * 300 + kk];
                    }
                }
            }
            *(half8*)&wo16F[a] = h;
        } else if (s < 54784) {  // bqkv [1024]
            int n = s - 53760;
            int g = n / 320, r = n - g * 320;
            float v = 0.f;
            if (r < 300) {
                if (g == 0) v = bq[r] * rs;
                else if (g == 1) v = bk[r];
                else if (g == 2) v = bv[r];
            }
            bqkv[n] = v;
        }
    } else if (bid < 614) {  // ---- repack2: Wva = Va @ Wo, 400 blocks ----
        int bt = bid - 214;
        int mt = bt / 20, nt = bt - mt * 20;
        int w = tid >> 6, lane = tid & 63;
        int lr = lane & 15, quad = lane >> 4;
        int m = mt * 16 + lr;   // Wva row
        int nn = nt * 16 + lr;  // Wva col (= Wo output dim)
        float4v acc = vz;
        int ks0 = (w < 2) ? w * 3 : 6 + (w - 2) * 2;
        int ksn = (w < 2) ? 3 : 2;
        for (int kk = 0; kk < ksn; ++kk) {
            int c = (ks0 + kk) * 32 + quad * 8;
            half8 af, bf;
#pragma unroll
            for (int j = 0; j < 8; ++j) {
                int cc = c + j;
                af[j] = (f16)((m < 300 && cc < 300) ? Va[m * 300 + cc] : 0.f);
                bf[j] = (f16)((nn < 300 && cc < 300) ? Wo[cc * 300 + nn] : 0.f);
            }
            acc = MFMA16(af, bf, acc);
        }
        red[w][lane] = acc;
        __syncthreads();
        if (w == 0) {
            float4v s = red[0][lane] + red[1][lane] + red[2][lane] + red[3][lane];
#pragma unroll
            for (int r = 0; r < 4; ++r) {
                int row = mt * 16 + quad * 4 + r;  // Wva row index (n of va GEMM)
                int col = nt * 16 + lr;            // Wva col index (k of va GEMM)
                int addr = ((row >> 4) * 10 + (col >> 5)) * 512 +
                           (((col >> 3) & 3) * 16 + (row & 15)) * 8 + (col & 7);
                wvaF[addr] = (f16)s[r];
            }
        }
    } else {  // ---- repack3: bva = Va @ bo + ba, 320 rows ----
        int j = (bid - 614) * 4 + (tid >> 6);  // 0..319
        int lane = tid & 63;
        float s = 0.f;
        if (j < 300) {
            for (int k = lane; k < 300; k += 64) s += Va[j * 300 + k] * bo[k];
        }
#pragma unroll
        for (int off = 1; off < 64; off <<= 1) s += __shfl_xor(s, off, 64);
        if (lane == 0) bva[j] = (j < 300) ? s + ba[j] : 0.f;
    }
}

// P4 helper: NT n-tiles x BOTH m-tiles per wave. All indices compile-time
// after unroll (no conditional arrays -> no scratch spill).
template <int NT>
__device__ __forceinline__ void p4_work(int tb, const f16* scratch,
                                        const f16* __restrict__ wvaF,
                                        const float* __restrict__ bva,
                                        const float* __restrict__ qw,
                                        float* aL, int lane, int lr, int quad) {
    const float4v vz = {0.f, 0.f, 0.f, 0.f};
    const f16* vp = wvaF + tb * 5120 + lane * 8;
    float pbva[NT], pqw[NT];
#pragma unroll
    for (int i = 0; i < NT; ++i) {
        int n = (tb + i) * 16 + lr;
        pbva[i] = bva[n];
        pqw[i] = (n < 300) ? qw[n] : 0.f;
    }
    float4v vacc[2][NT];
#pragma unroll
    for (int mt = 0; mt < 2; ++mt)
#pragma unroll
        for (int i = 0; i < NT; ++i) vacc[mt][i] = vz;
#pragma unroll
    for (int ks = 0; ks < 10; ++ks) {
        half8 a0 = *(const half8*)&scratch[lr * 328 + ks * 32 + quad * 8];
        half8 a1 = *(const half8*)&scratch[(16 + lr) * 328 + ks * 32 + quad * 8];
#pragma unroll
        for (int i = 0; i < NT; ++i) {
            half8 bf = *(const half8*)(vp + i * 5120 + ks * 512);
            vacc[0][i] = MFMA16(a0, bf, vacc[0][i]);
            vacc[1][i] = MFMA16(a1, bf, vacc[1][i]);
        }
    }
    float ps[2][4] = {{0.f, 0.f, 0.f, 0.f}, {0.f, 0.f, 0.f, 0.f}};
#pragma unroll
    for (int i = 0; i < NT; ++i)
#pragma unroll
        for (int mt = 0; mt < 2; ++mt)
#pragma unroll
            for (int r = 0; r < 4; ++r)
                ps[mt][r] += fast_tanh(vacc[mt][i][r] + pbva[i]) * pqw[i];
#pragma unroll
    for (int mt = 0; mt < 2; ++mt)
#pragma unroll
        for (int r = 0; r < 4; ++r)
#pragma unroll
            for (int off = 1; off < 16; off <<= 1)
                ps[mt][r] += __shfl_xor(ps[mt][r], off, 64);
    if (lr == 0) {
#pragma unroll
        for (int mt = 0; mt < 2; ++mt)
#pragma unroll
            for (int r = 0; r < 4; ++r)
                atomicAdd(&aL[mt * 16 + quad * 4 + r], ps[mt][r]);
    }
}

// ---- fused gather + QKV GEMM + attention + va + softmax + pool ----
// 1 item/block. LDS: qL/kL [6*32][72], vT [6*64][32] = 80,064 B -> 2 blocks/CU.
// P1 wave-specialized with branches inlined in the kernel body (no out-param
// function): acc is a plain local, every index compile-time after unroll.
__global__ __launch_bounds__(512, 4) void qkvattn_kernel(
    const int* __restrict__ title, const float* __restrict__ emb,
    const float* __restrict__ pos,
    const f16* __restrict__ wqkvF, const float* __restrict__ bqkv,
    const f16* __restrict__ wvaF, const float* __restrict__ bva,
    const float* __restrict__ qw, f16* __restrict__ cbar) {
    __shared__ __align__(16) f16 qL[6 * 32 * 72];
    __shared__ __align__(16) f16 kL[6 * 32 * 72];
    __shared__ __align__(16) f16 vT[6 * 64 * 32];  // first 20480 B alias xA staging
    __shared__ float aL[32];
    const int ib = blockIdx.x, tid = threadIdx.x;
    const int w = tid >> 6, lane = tid & 63, lr = lane & 15, quad = lane >> 4;
    const float4v vz = {0.f, 0.f, 0.f, 0.f};
    const int4v z4 = {0, 0, 0, 0};
    f16* xA = vT;  // [20 fragblks][64 lanes][8] f16 = 20480 B

    // --- P0: gather x = emb[title]+pos into LDS frag layout (aliases vT) ---
    for (int u = tid; u < 1280; u += 512) {
        int fragblk = u >> 6, lu = u & 63;
        int mt = fragblk / 10, ks = fragblk - mt * 10;
        int row = mt * 16 + (lu & 15);        // l index 0..31
        int col = ks * 32 + (lu >> 4) * 8;
        int t = title[ib * 32 + row];
        half8 h;
        if (col + 8 <= 300) {
            float4v e0 = *(const float4v*)&emb[t * 300 + col];
            float4v e1 = *(const float4v*)&emb[t * 300 + col + 4];
            float4v p0 = *(const float4v*)&pos[row * 300 + col];
            float4v p1 = *(const float4v*)&pos[row * 300 + col + 4];
#pragma unroll
            for (int j = 0; j < 4; ++j) {
                h[j] = (f16)(e0[j] + p0[j]);
                h[4 + j] = (f16)(e1[j] + p1[j]);
            }
        } else {
#pragma unroll
            for (int j = 0; j < 8; ++j) {
                int cc = col + j;
                h[j] = (f16)((cc < 300) ? emb[t * 300 + cc] + pos[row * 300 + cc] : 0.f);
            }
        }
        *(half8*)&xA[u * 8] = h;
    }
    // qL/kL pad zeroing (cols 50..63) — disjoint from P1 epilogue writes
    for (int i = tid; i < 1344; i += 512) {  // 192 hrows x 7 dwords
        int hrow = i / 7, c = i - hrow * 7;
        ((int*)&qL[hrow * 72 + 50])[c] = 0;
        ((int*)&kL[hrow * 72 + 50])[c] = 0;
    }
    if (tid < 32) aL[tid] = 0.f;
    // hoist bqkv bias loads (global, independent of LDS)
    float bb[8];
#pragma unroll
    for (int j = 0; j < 8; ++j) bb[j] = bqkv[(w * 8 + j) * 16 + lr];
    __syncthreads();  // xA visible

    // --- Phase 1: QKV GEMM, M=32, wave-specialized tile sets (inlined) ---
    float4v acc[2][8];
#pragma unroll
    for (int mt = 0; mt < 2; ++mt)
#pragma unroll
        for (int j = 0; j < 8; ++j) acc[mt][j] = vz;
    if (w < 7) {
        const f16* bp = wqkvF + (w * 8) * 5120 + lane * 8;
#pragma unroll
        for (int ks = 0; ks < 10; ++ks) {
            half8 a0 = *(const half8*)&xA[(ks * 64 + lane) * 8];
            half8 a1 = *(const half8*)&xA[((10 + ks) * 64 + lane) * 8];
#pragma unroll
            for (int j = 0; j < 8; ++j) {
                half8 bf = *(const half8*)(bp + j * 5120 + ks * 512);
                acc[0][j] = MFMA16(a0, bf, acc[0][j]);
                acc[1][j] = MFMA16(a1, bf, acc[1][j]);
            }
        }
    } else {
        const f16* bp = wqkvF + 56 * 5120 + lane * 8;  // tiles 56..58; 59..63 pure pad
#pragma unroll
        for (int ks = 0; ks < 10; ++ks) {
            half8 a0 = *(const half8*)&xA[(ks * 64 + lane) * 8];
            half8 a1 = *(const half8*)&xA[((10 + ks) * 64 + lane) * 8];
#pragma unroll
            for (int j = 0; j < 3; ++j) {
                half8 bf = *(const half8*)(bp + j * 5120 + ks * 512);
                acc[0][j] = MFMA16(a0, bf, acc[0][j]);
                acc[1][j] = MFMA16(a1, bf, acc[1][j]);
            }
        }
    }
    __syncthreads();  // all xA reads done; vT may now be overwritten

    // vT pad zeroing (rows d=50..63 per head)
    for (int i = tid; i < 336; i += 512) {
        int t = i >> 2, c4 = i & 3;
        int h = t / 14, d = 50 + (t - (t / 14) * 14);
        ((int4v*)&vT[(h * 64 + d) * 32])[c4] = z4;
    }
    // epilogue: scatter q/k/v into LDS (wi is wave-uniform per j: 8 | 20)
#pragma unroll
    for (int j = 0; j < 8; ++j) {
        int tile = w * 8 + j;
        int wi = tile / 20;
        int n = tile * 16 + lr;
        int cc = n - wi * 320;
        if (wi < 3 && cc < 300) {
            int h = cc / 50, d = cc - h * 50;
            if (wi == 2) {  // v: packed b64 write, XOR-swizzled on byte bits 4-5
#pragma unroll
                for (int mt = 0; mt < 2; ++mt) {
                    int row0 = mt * 16 + quad * 4;
                    half4 pk;
#pragma unroll
                    for (int r = 0; r < 4; ++r) pk[r] = (f16)(acc[mt][j][r] + bb[j]);
                    int idx = (h * 64 + d) * 32 + row0;
                    int byt = (idx * 2) ^ (((d >> 2) & 3) << 4);
                    *(half4*)((char*)vT + byt) = pk;
                }
            } else {
                f16* dst = (wi == 0) ? qL : kL;
#pragma unroll
                for (int mt = 0; mt < 2; ++mt)
#pragma unroll
                    for (int r = 0; r < 4; ++r) {
                        int row = mt * 16 + quad * 4 + r;
                        dst[(h * 32 + row) * 72 + d] = (f16)(acc[mt][j][r] + bb[j]);
                    }
            }
        }
    }
    __syncthreads();

    // --- Phase 2: wave hh (<6) computes scores + softmax -> P (aliases qL) ---
    const int hh = w;
    if (w < 6) {
        float4v s00 = vz, s01 = vz, s10 = vz, s11 = vz;
#pragma unroll
        for (int ks = 0; ks < 2; ++ks) {
            int c = ks * 32 + quad * 8;
            half8 aq0 = *(const half8*)&qL[(hh * 32 + lr) * 72 + c];
            half8 aq1 = *(const half8*)&qL[(hh * 32 + 16 + lr) * 72 + c];
            half8 bk0 = *(const half8*)&kL[(hh * 32 + lr) * 72 + c];
            half8 bk1 = *(const half8*)&kL[(hh * 32 + 16 + lr) * 72 + c];
            s00 = MFMA16(aq0, bk0, s00);
            s01 = MFMA16(aq0, bk1, s01);
            s10 = MFMA16(aq1, bk0, s10);
            s11 = MFMA16(aq1, bk1, s11);
        }
        f16* ph = qL + hh * 32 * 72;
#pragma unroll
        for (int mt = 0; mt < 2; ++mt) {
            float4v sv0 = mt ? s10 : s00;
            float4v sv1 = mt ? s11 : s01;
#pragma unroll
            for (int r = 0; r < 4; ++r) {
                float v0 = sv0[r], v1 = sv1[r];
                float m = fmaxf(v0, v1);
#pragma unroll
                for (int off = 1; off < 16; off <<= 1) m = fmaxf(m, __shfl_xor(m, off, 64));
                float e0 = __expf(v0 - m), e1 = __expf(v1 - m);
                float ss = e0 + e1;
#pragma unroll
                for (int off = 1; off < 16; off <<= 1) ss += __shfl_xor(ss, off, 64);
                float inv = 1.0f / ss;
                int row = mt * 16 + quad * 4 + r;
                ph[row * 40 + lr] = (f16)(e0 * inv);
                ph[row * 40 + 16 + lr] = (f16)(e1 * inv);
            }
        }
    }
    __syncthreads();

    // --- Phase 3: ctx = P @ V -> row-major scratch (reuses kL, [32][328]) ---
    f16* scratch = kL;
    for (int i = tid; i < 32 * 28; i += 512) {  // zero pad cols 300..327
        int row = i / 28, cc = 300 + (i - row * 28);
        scratch[row * 328 + cc] = (f16)0.f;
    }
    if (w < 6) {
        int h = hh;
        f16* ph = qL + hh * 32 * 72;
        half8 aw0 = *(const half8*)&ph[lr * 40 + quad * 8];
        half8 aw1 = *(const half8*)&ph[(16 + lr) * 40 + quad * 8];
        float4v c0[4], c1[4];
#pragma unroll
        for (int nt = 0; nt < 4; ++nt) { c0[nt] = vz; c1[nt] = vz; }
#pragma unroll
        for (int nt = 0; nt < 4; ++nt) {
            int rIdx = nt * 16 + lr;
            int idx = (hh * 64 + rIdx) * 32 + quad * 8;
            int byt = (idx * 2) ^ (((rIdx >> 2) & 3) << 4);
            half8 bvf = *(const half8*)((const char*)vT + byt);
            c0[nt] = MFMA16(aw0, bvf, c0[nt]);
            c1[nt] = MFMA16(aw1, bvf, c1[nt]);
        }
#pragma unroll
        for (int mt = 0; mt < 2; ++mt)
#pragma unroll
            for (int nt = 0; nt < 4; ++nt)
#pragma unroll
                for (int r = 0; r < 4; ++r) {
                    int d = nt * 16 + lr;
                    if (d < 50) {
                        int row = mt * 16 + quad * 4 + r;
                        float4v cv = mt ? c1[nt] : c0[nt];
                        scratch[row * 328 + h * 50 + d] = (f16)cv[r];
                    }
                }
    }
    __syncthreads();

    // --- Phase 4: va GEMM (deduped): wave w owns disjoint n-tiles, both m-tiles ---
    if (w < 4) p4_work<3>(w * 3, scratch, wvaF, bva, qw, aL, lane, lr, quad);
    else       p4_work<2>(12 + (w - 4) * 2, scratch, wvaF, bva, qw, aL, lane, lr, quad);
    __syncthreads();

    // --- Phase 5+6 fused: redundant 32-softmax per wave, alpha via shfl ---
    {
        float av = aL[lane & 31];
        float m5 = av;
#pragma unroll
        for (int off = 1; off < 32; off <<= 1) m5 = fmaxf(m5, __shfl_xor(m5, off, 32));
        float e5 = __expf(av - m5);
        float ss5 = e5;
#pragma unroll
        for (int off = 1; off < 32; off <<= 1) ss5 += __shfl_xor(ss5, off, 32);
        float al = e5 / ss5;  // lane (l&31) holds alpha[l&31]
        if (tid < 320) {
            int d = tid;
            float acc6 = 0.f;
#pragma unroll
            for (int l = 0; l < 32; ++l)
                acc6 += __shfl(al, l, 32) * (float)scratch[l * 328 + d];
            cbar[ib * 320 + d] = (f16)acc6;
        }
    }
}

// ------- out = cbar @ Wo^T + bo, f32 [4096][300]; 256 blocks x M=16 -------
__global__ __launch_bounds__(512) void out_kernel(
    const f16* __restrict__ cbar, const f16* __restrict__ wo16F,
    const float* __restrict__ bo, float* __restrict__ out) {
    __shared__ __align__(16) f16 cA[16 * 328];
    const int mb = blockIdx.x, tid = threadIdx.x;  // 256 blocks, M=16
    const int w = tid >> 6, lane = tid & 63, lr = lane & 15, quad = lane >> 4;
    for (int i = tid; i < 640; i += 512) {
        int row = i / 40, g = i - row * 40;
        *(half8*)&cA[row * 328 + g * 8] = *(const half8*)&cbar[(mb * 16 + row) * 320 + g * 8];
    }
    __syncthreads();
    const float4v vz = {0.f, 0.f, 0.f, 0.f};
    for (int t = w; t < 19; t += 8) {
        float4v acc = vz;
#pragma unroll
        for (int ks = 0; ks < 10; ++ks) {
            half8 a = *(const half8*)&cA[lr * 328 + ks * 32 + quad * 8];
            half8 bf = *(const half8*)&wo16F[((t * 10 + ks) * 64 + lane) * 8];
            acc = MFMA16(a, bf, acc);
        }
        int n = t * 16 + lr;
        if (n < 300) {
            float bb = bo[n];
#pragma unroll
            for (int r = 0; r < 4; ++r)
                out[(mb * 16 + quad * 4 + r) * 300 + n] = acc[r] + bb;
        }
    }
}

// ---------------- host launcher ----------------
extern "C" void kernel_launch(void* const* d_in, const int* in_sizes, int n_in,
                              void* d_out, int out_size, void* d_ws, size_t ws_size,
                              hipStream_t stream) {
    const int* title = (const int*)d_in[0];
    const float* emb = (const float*)d_in[1];
    const float* pos = (const float*)d_in[2];
    const float* Wq = (const float*)d_in[3];
    const float* bq = (const float*)d_in[4];
    const float* Wk = (const float*)d_in[5];
    const float* bk = (const float*)d_in[6];
    const float* Wv = (const float*)d_in[7];
    const float* bv = (const float*)d_in[8];
    const float* Wo = (const float*)d_in[9];
    const float* bo = (const float*)d_in[10];
    const float* Va = (const float*)d_in[11];
    const float* ba = (const float*)d_in[12];
    const float* qw = (const float*)d_in[13];
    char* ws = (char*)d_ws;
    float* out = (float*)d_out;

    f16* wqkvF = (f16*)(ws + WQKV_OFF);
    float* bqkv = (float*)(ws + BQKV_OFF);
    f16* wo16F = (f16*)(ws + WO_OFF);
    f16* wvaF = (f16*)(ws + WVA_OFF);
    float* bva = (float*)(ws + BVA_OFF);
    f16* cbar = (f16*)(ws + CBAR_OFF);

    repack_all<<<694, 256, 0, stream>>>(Wq, Wk, Wv, Wo, bq, bk, bv, Va, bo, ba,
                                        wqkvF, wo16F, bqkv, wvaF, bva);
    qkvattn_kernel<<<4096, 512, 0, stream>>>(title, emb, pos, wqkvF, bqkv, wvaF, bva,
                                             qw, cbar);
    out_kernel<<<256, 512, 0, stream>>>(cbar, wo16F, bo, out);
}

// Round 12
// 384.853 us; speedup vs baseline: 1.1085x; 1.0139x over previous
//
#include <hip/hip_runtime.h>
#include <math.h>

typedef _Float16 f16;
typedef _Float16 half8 __attribute__((ext_vector_type(8)));
typedef _Float16 half4 __attribute__((ext_vector_type(4)));
typedef float float4v __attribute__((ext_vector_type(4)));
typedef int int4v __attribute__((ext_vector_type(4)));

#define MFMA16(a, b, c) __builtin_amdgcn_mfma_f32_16x16x32_f16((a), (b), (c), 0, 0, 0)

// problem: B=4096 L=32 V=50000 D=300 H=6 HD=50 ; K padded to 320
// Fragment-swizzled layout: element (n, k) of a [Nt*16][320] matrix lives at
//   F[((n>>4)*10 + (k>>5))*512 + (((k>>3)&3)*16 + (n&15))*8 + (k&7)]

// ---------------- ws layout (bytes) ----------------
#define WQKV_OFF 0u          // f16 frag-swizzled [64 ntiles] (q*rs | k | v rows, pads 0)
#define BQKV_OFF 655360u     // f32 [1024]
#define WO_OFF   659456u     // f16 frag-swizzled [20 ntiles] Wo
#define WVA_OFF  864256u     // f16 frag-swizzled [20 ntiles] Va@Wo
#define BVA_OFF  1069056u    // f32 [320]  Va@bo+ba (pads 0)
#define CBAR_OFF 1070336u    // f16 [4096][320] row-major

// fast tanh via exp2-based __expf + hardware rcp (output feeds f16 paths;
// v_rcp_f32 rel. err ~2^-22 is far below f16 eps)
__device__ __forceinline__ float fast_tanh(float x) {
    float e = __expf(2.f * x);
    return 1.f - 2.f * __builtin_amdgcn_rcpf(e + 1.f);
}

// ------- repack_all: vectorized repack1 | 4x-parallel repack2 | repack3 ---
__global__ __launch_bounds__(256) void repack_all(
    const float* __restrict__ Wq, const float* __restrict__ Wk,
    const float* __restrict__ Wv, const float* __restrict__ Wo,
    const float* __restrict__ bq, const float* __restrict__ bk,
    const float* __restrict__ bv, const float* __restrict__ Va,
    const float* __restrict__ bo, const float* __restrict__ ba,
    f16* __restrict__ wqkvF, f16* __restrict__ wo16F, float* __restrict__ bqkv,
    f16* __restrict__ wvaF, float* __restrict__ bva) {
    __shared__ float4v red[4][64];
    const int bid = blockIdx.x, tid = threadIdx.x;
    const float rs = 0.14142135623730951f;  // 1/sqrt(50)
    const float4v vz = {0.f, 0.f, 0.f, 0.f};
    if (bid < 214) {
        int s = bid * 256 + tid;
        if (s < 40960) {  // wqkvF: 40960 half8 slots
            int a = s * 8;
            int ntile = a / 5120, rem = a - ntile * 5120;
            int ks = rem / 512, r2 = rem - ks * 512;
            int lane = r2 >> 3;
            int n = ntile * 16 + (lane & 15);
            int k = ks * 32 + (lane >> 4) * 8;
            int g = n / 320, r = n - g * 320;
            half8 h;
#pragma unroll
            for (int j = 0; j < 8; ++j) h[j] = (f16)0.f;
            if (g < 3 && r < 300) {
                const float* W = (g == 0) ? Wq : (g == 1) ? Wk : Wv;
                float sc = (g == 0) ? rs : 1.f;
                if (k + 8 <= 300) {
                    float4v v0 = *(const float4v*)&W[r * 300 + k];
                    float4v v1 = *(const float4v*)&W[r * 300 + k + 4];
#pragma unroll
                    for (int j = 0; j < 4; ++j) {
                        h[j] = (f16)(v0[j] * sc);
                        h[4 + j] = (f16)(v1[j] * sc);
                    }
                } else {
#pragma unroll
                    for (int j = 0; j < 8; ++j) {
                        int kk = k + j;
                        if (kk < 300) h[j] = (f16)(W[r * 300 + kk] * sc);
                    }
                }
            }
            *(half8*)&wqkvF[a] = h;
        } else if (s < 53760) {  // wo16F: 12800 half8 slots
            int a = (s - 40960) * 8;
            int ntile = a / 5120, rem = a - ntile * 5120;
            int ks = rem / 512, r2 = rem - ks * 512;
            int lane = r2 >> 3;
            int n = ntile * 16 + (lane & 15);
            int k = ks * 32 + (lane >> 4) * 8;
            half8 h;
#pragma unroll
            for (int j = 0; j < 8; ++j) h[j] = (f16)0.f;
            if (n < 300) {
                if (k + 8 <= 300) {
                    float4v v0 = *(const float4v*)&Wo[n * 300 + k];
                    float4v v1 = *(const float4v*)&Wo[n * 300 + k + 4];
#pragma unroll
                    for (int j = 0; j < 4; ++j) {
                        h[j] = (f16)v0[j];
                        h[4 + j] = (f16)v1[j];
                    }
                } else {
#pragma unroll
                    for (int j = 0; j < 8; ++j) {
                        int kk = k + j;
                        if (kk < 300) h[j] = (f16)Wo[n * 300 + kk];
                    }
                }
            }
            *(half8*)&wo16F[a] = h;
        } else if (s < 54784) {  // bqkv [1024]
            int n = s - 53760;
            int g = n / 320, r = n - g * 320;
            float v = 0.f;
            if (r < 300) {
                if (g == 0) v = bq[r] * rs;
                else if (g == 1) v = bk[r];
                else if (g == 2) v = bv[r];
            }
            bqkv[n] = v;
        }
    } else if (bid < 614) {  // ---- repack2: Wva = Va @ Wo, 400 blocks ----
        int bt = bid - 214;
        int mt = bt / 20, nt = bt - mt * 20;
        int w = tid >> 6, lane = tid & 63;
        int lr = lane & 15, quad = lane >> 4;
        int m = mt * 16 + lr;   // Wva row
        int nn = nt * 16 + lr;  // Wva col (= Wo output dim)
        float4v acc = vz;
        int ks0 = (w < 2) ? w * 3 : 6 + (w - 2) * 2;
        int ksn = (w < 2) ? 3 : 2;
        for (int kk = 0; kk < ksn; ++kk) {
            int c = (ks0 + kk) * 32 + quad * 8;
            half8 af, bf;
#pragma unroll
            for (int j = 0; j < 8; ++j) {
                int cc = c + j;
                af[j] = (f16)((m < 300 && cc < 300) ? Va[m * 300 + cc] : 0.f);
                bf[j] = (f16)((nn < 300 && cc < 300) ? Wo[cc * 300 + nn] : 0.f);
            }
            acc = MFMA16(af, bf, acc);
        }
        red[w][lane] = acc;
        __syncthreads();
        if (w == 0) {
            float4v s = red[0][lane] + red[1][lane] + red[2][lane] + red[3][lane];
#pragma unroll
            for (int r = 0; r < 4; ++r) {
                int row = mt * 16 + quad * 4 + r;  // Wva row index (n of va GEMM)
                int col = nt * 16 + lr;            // Wva col index (k of va GEMM)
                int addr = ((row >> 4) * 10 + (col >> 5)) * 512 +
                           (((col >> 3) & 3) * 16 + (row & 15)) * 8 + (col & 7);
                wvaF[addr] = (f16)s[r];
            }
        }
    } else {  // ---- repack3: bva = Va @ bo + ba, 320 rows ----
        int j = (bid - 614) * 4 + (tid >> 6);  // 0..319
        int lane = tid & 63;
        float s = 0.f;
        if (j < 300) {
            for (int k = lane; k < 300; k += 64) s += Va[j * 300 + k] * bo[k];
        }
#pragma unroll
        for (int off = 1; off < 64; off <<= 1) s += __shfl_xor(s, off, 64);
        if (lane == 0) bva[j] = (j < 300) ? s + ba[j] : 0.f;
    }
}

// P4 helper: NT n-tiles x BOTH m-tiles per wave. All indices compile-time
// after unroll (no conditional arrays -> no scratch spill).
template <int NT>
__device__ __forceinline__ void p4_work(int tb, const f16* scratch,
                                        const f16* __restrict__ wvaF,
                                        const float* __restrict__ bva,
                                        const float* __restrict__ qw,
                                        float* aL, int lane, int lr, int quad) {
    const float4v vz = {0.f, 0.f, 0.f, 0.f};
    const f16* vp = wvaF + tb * 5120 + lane * 8;
    float pbva[NT], pqw[NT];
#pragma unroll
    for (int i = 0; i < NT; ++i) {
        int n = (tb + i) * 16 + lr;
        pbva[i] = bva[n];
        pqw[i] = (n < 300) ? qw[n] : 0.f;
    }
    float4v vacc[2][NT];
#pragma unroll
    for (int mt = 0; mt < 2; ++mt)
#pragma unroll
        for (int i = 0; i < NT; ++i) vacc[mt][i] = vz;
#pragma unroll
    for (int ks = 0; ks < 10; ++ks) {
        half8 a0 = *(const half8*)&scratch[lr * 328 + ks * 32 + quad * 8];
        half8 a1 = *(const half8*)&scratch[(16 + lr) * 328 + ks * 32 + quad * 8];
#pragma unroll
        for (int i = 0; i < NT; ++i) {
            half8 bf = *(const half8*)(vp + i * 5120 + ks * 512);
            vacc[0][i] = MFMA16(a0, bf, vacc[0][i]);
            vacc[1][i] = MFMA16(a1, bf, vacc[1][i]);
        }
    }
    float ps[2][4] = {{0.f, 0.f, 0.f, 0.f}, {0.f, 0.f, 0.f, 0.f}};
#pragma unroll
    for (int i = 0; i < NT; ++i)
#pragma unroll
        for (int mt = 0; mt < 2; ++mt)
#pragma unroll
            for (int r = 0; r < 4; ++r)
                ps[mt][r] += fast_tanh(vacc[mt][i][r] + pbva[i]) * pqw[i];
#pragma unroll
    for (int mt = 0; mt < 2; ++mt)
#pragma unroll
        for (int r = 0; r < 4; ++r)
#pragma unroll
            for (int off = 1; off < 16; off <<= 1)
                ps[mt][r] += __shfl_xor(ps[mt][r], off, 64);
    if (lr == 0) {
#pragma unroll
        for (int mt = 0; mt < 2; ++mt)
#pragma unroll
            for (int r = 0; r < 4; ++r)
                atomicAdd(&aL[mt * 16 + quad * 4 + r], ps[mt][r]);
    }
}

// ---- fused gather + QKV GEMM + attention + va + softmax + pool ----
// 1 item/block. LDS: qL/kL [6*32][72], vT [6*64][32] = 80,064 B -> 2 blocks/CU.
// P1 wave-specialized, branches inlined. rcp-based divides on all hot paths.
__global__ __launch_bounds__(512, 4) void qkvattn_kernel(
    const int* __restrict__ title, const float* __restrict__ emb,
    const float* __restrict__ pos,
    const f16* __restrict__ wqkvF, const float* __restrict__ bqkv,
    const f16* __restrict__ wvaF, const float* __restrict__ bva,
    const float* __restrict__ qw, f16* __restrict__ cbar) {
    __shared__ __align__(16) f16 qL[6 * 32 * 72];
    __shared__ __align__(16) f16 kL[6 * 32 * 72];
    __shared__ __align__(16) f16 vT[6 * 64 * 32];  // first 20480 B alias xA staging
    __shared__ float aL[32];
    const int ib = blockIdx.x, tid = threadIdx.x;
    const int w = tid >> 6, lane = tid & 63, lr = lane & 15, quad = lane >> 4;
    const float4v vz = {0.f, 0.f, 0.f, 0.f};
    const int4v z4 = {0, 0, 0, 0};
    f16* xA = vT;  // [20 fragblks][64 lanes][8] f16 = 20480 B

    // --- P0: gather x = emb[title]+pos into LDS frag layout (aliases vT) ---
    for (int u = tid; u < 1280; u += 512) {
        int fragblk = u >> 6, lu = u & 63;
        int mt = fragblk / 10, ks = fragblk - mt * 10;
        int row = mt * 16 + (lu & 15);        // l index 0..31
        int col = ks * 32 + (lu >> 4) * 8;
        int t = title[ib * 32 + row];
        half8 h;
        if (col + 8 <= 300) {
            float4v e0 = *(const float4v*)&emb[t * 300 + col];
            float4v e1 = *(const float4v*)&emb[t * 300 + col + 4];
            float4v p0 = *(const float4v*)&pos[row * 300 + col];
            float4v p1 = *(const float4v*)&pos[row * 300 + col + 4];
#pragma unroll
            for (int j = 0; j < 4; ++j) {
                h[j] = (f16)(e0[j] + p0[j]);
                h[4 + j] = (f16)(e1[j] + p1[j]);
            }
        } else {
#pragma unroll
            for (int j = 0; j < 8; ++j) {
                int cc = col + j;
                h[j] = (f16)((cc < 300) ? emb[t * 300 + cc] + pos[row * 300 + cc] : 0.f);
            }
        }
        *(half8*)&xA[u * 8] = h;
    }
    // qL/kL pad zeroing (cols 50..63) — disjoint from P1 epilogue writes
    for (int i = tid; i < 1344; i += 512) {  // 192 hrows x 7 dwords
        int hrow = i / 7, c = i - hrow * 7;
        ((int*)&qL[hrow * 72 + 50])[c] = 0;
        ((int*)&kL[hrow * 72 + 50])[c] = 0;
    }
    if (tid < 32) aL[tid] = 0.f;
    // hoist bqkv bias loads (global, independent of LDS)
    float bb[8];
#pragma unroll
    for (int j = 0; j < 8; ++j) bb[j] = bqkv[(w * 8 + j) * 16 + lr];
    __syncthreads();  // xA visible

    // --- Phase 1: QKV GEMM, M=32, wave-specialized tile sets (inlined) ---
    float4v acc[2][8];
#pragma unroll
    for (int mt = 0; mt < 2; ++mt)
#pragma unroll
        for (int j = 0; j < 8; ++j) acc[mt][j] = vz;
    if (w < 7) {
        const f16* bp = wqkvF + (w * 8) * 5120 + lane * 8;
#pragma unroll
        for (int ks = 0; ks < 10; ++ks) {
            half8 a0 = *(const half8*)&xA[(ks * 64 + lane) * 8];
            half8 a1 = *(const half8*)&xA[((10 + ks) * 64 + lane) * 8];
#pragma unroll
            for (int j = 0; j < 8; ++j) {
                half8 bf = *(const half8*)(bp + j * 5120 + ks * 512);
                acc[0][j] = MFMA16(a0, bf, acc[0][j]);
                acc[1][j] = MFMA16(a1, bf, acc[1][j]);
            }
        }
    } else {
        const f16* bp = wqkvF + 56 * 5120 + lane * 8;  // tiles 56..58; 59..63 pure pad
#pragma unroll
        for (int ks = 0; ks < 10; ++ks) {
            half8 a0 = *(const half8*)&xA[(ks * 64 + lane) * 8];
            half8 a1 = *(const half8*)&xA[((10 + ks) * 64 + lane) * 8];
#pragma unroll
            for (int j = 0; j < 3; ++j) {
                half8 bf = *(const half8*)(bp + j * 5120 + ks * 512);
                acc[0][j] = MFMA16(a0, bf, acc[0][j]);
                acc[1][j] = MFMA16(a1, bf, acc[1][j]);
            }
        }
    }
    __syncthreads();  // all xA reads done; vT may now be overwritten

    // vT pad zeroing (rows d=50..63 per head)
    for (int i = tid; i < 336; i += 512) {
        int t = i >> 2, c4 = i & 3;
        int h = t / 14, d = 50 + (t - (t / 14) * 14);
        ((int4v*)&vT[(h * 64 + d) * 32])[c4] = z4;
    }
    // epilogue: scatter q/k/v into LDS (wi is wave-uniform per j: 8 | 20)
#pragma unroll
    for (int j = 0; j < 8; ++j) {
        int tile = w * 8 + j;
        int wi = tile / 20;
        int n = tile * 16 + lr;
        int cc = n - wi * 320;
        if (wi < 3 && cc < 300) {
            int h = cc / 50, d = cc - h * 50;
            if (wi == 2) {  // v: packed b64 write, XOR-swizzled on byte bits 4-5
#pragma unroll
                for (int mt = 0; mt < 2; ++mt) {
                    int row0 = mt * 16 + quad * 4;
                    half4 pk;
#pragma unroll
                    for (int r = 0; r < 4; ++r) pk[r] = (f16)(acc[mt][j][r] + bb[j]);
                    int idx = (h * 64 + d) * 32 + row0;
                    int byt = (idx * 2) ^ (((d >> 2) & 3) << 4);
                    *(half4*)((char*)vT + byt) = pk;
                }
            } else {
                f16* dst = (wi == 0) ? qL : kL;
#pragma unroll
                for (int mt = 0; mt < 2; ++mt)
#pragma unroll
                    for (int r = 0; r < 4; ++r) {
                        int row = mt * 16 + quad * 4 + r;
                        dst[(h * 32 + row) * 72 + d] = (f16)(acc[mt][j][r] + bb[j]);
                    }
            }
        }
    }
    __syncthreads();

    // --- Phase 2: wave hh (<6) computes scores + softmax -> P (aliases qL) ---
    const int hh = w;
    if (w < 6) {
        float4v s00 = vz, s01 = vz, s10 = vz, s11 = vz;
#pragma unroll
        for (int ks = 0; ks < 2; ++ks) {
            int c = ks * 32 + quad * 8;
            half8 aq0 = *(const half8*)&qL[(hh * 32 + lr) * 72 + c];
            half8 aq1 = *(const half8*)&qL[(hh * 32 + 16 + lr) * 72 + c];
            half8 bk0 = *(const half8*)&kL[(hh * 32 + lr) * 72 + c];
            half8 bk1 = *(const half8*)&kL[(hh * 32 + 16 + lr) * 72 + c];
            s00 = MFMA16(aq0, bk0, s00);
            s01 = MFMA16(aq0, bk1, s01);
            s10 = MFMA16(aq1, bk0, s10);
            s11 = MFMA16(aq1, bk1, s11);
        }
        f16* ph = qL + hh * 32 * 72;
#pragma unroll
        for (int mt = 0; mt < 2; ++mt) {
            float4v sv0 = mt ? s10 : s00;
            float4v sv1 = mt ? s11 : s01;
#pragma unroll
            for (int r = 0; r < 4; ++r) {
                float v0 = sv0[r], v1 = sv1[r];
                float m = fmaxf(v0, v1);
#pragma unroll
                for (int off = 1; off < 16; off <<= 1) m = fmaxf(m, __shfl_xor(m, off, 64));
                float e0 = __expf(v0 - m), e1 = __expf(v1 - m);
                float ss = e0 + e1;
#pragma unroll
                for (int off = 1; off < 16; off <<= 1) ss += __shfl_xor(ss, off, 64);
                float inv = __builtin_amdgcn_rcpf(ss);
                int row = mt * 16 + quad * 4 + r;
                ph[row * 40 + lr] = (f16)(e0 * inv);
                ph[row * 40 + 16 + lr] = (f16)(e1 * inv);
            }
        }
    }
    __syncthreads();

    // --- Phase 3: ctx = P @ V -> row-major scratch (reuses kL, [32][328]) ---
    f16* scratch = kL;
    for (int i = tid; i < 32 * 28; i += 512) {  // zero pad cols 300..327
        int row = i / 28, cc = 300 + (i - row * 28);
        scratch[row * 328 + cc] = (f16)0.f;
    }
    if (w < 6) {
        int h = hh;
        f16* ph = qL + hh * 32 * 72;
        half8 aw0 = *(const half8*)&ph[lr * 40 + quad * 8];
        half8 aw1 = *(const half8*)&ph[(16 + lr) * 40 + quad * 8];
        float4v c0[4], c1[4];
#pragma unroll
        for (int nt = 0; nt < 4; ++nt) { c0[nt] = vz; c1[nt] = vz; }
#pragma unroll
        for (int nt = 0; nt < 4; ++nt) {
            int rIdx = nt * 16 + lr;
            int idx = (hh * 64 + rIdx) * 32 + quad * 8;
            int byt = (idx * 2) ^ (((rIdx >> 2) & 3) << 4);
            half8 bvf = *(const half8*)((const char*)vT + byt);
            c0[nt] = MFMA16(aw0, bvf, c0[nt]);
            c1[nt] = MFMA16(aw1, bvf, c1[nt]);
        }
#pragma unroll
        for (int mt = 0; mt < 2; ++mt)
#pragma unroll
            for (int nt = 0; nt < 4; ++nt)
#pragma unroll
                for (int r = 0; r < 4; ++r) {
                    int d = nt * 16 + lr;
                    if (d < 50) {
                        int row = mt * 16 + quad * 4 + r;
                        float4v cv = mt ? c1[nt] : c0[nt];
                        scratch[row * 328 + h * 50 + d] = (f16)cv[r];
                    }
                }
    }
    __syncthreads();

    // --- Phase 4: va GEMM (deduped): wave w owns disjoint n-tiles, both m-tiles ---
    if (w < 4) p4_work<3>(w * 3, scratch, wvaF, bva, qw, aL, lane, lr, quad);
    else       p4_work<2>(12 + (w - 4) * 2, scratch, wvaF, bva, qw, aL, lane, lr, quad);
    __syncthreads();

    // --- Phase 5+6 fused: redundant 32-softmax per wave, alpha via shfl;
    //     pooling uses 4 split accumulators to break the serial FMA chain ---
    {
        float av = aL[lane & 31];
        float m5 = av;
#pragma unroll
        for (int off = 1; off < 32; off <<= 1) m5 = fmaxf(m5, __shfl_xor(m5, off, 32));
        float e5 = __expf(av - m5);
        float ss5 = e5;
#pragma unroll
        for (int off = 1; off < 32; off <<= 1) ss5 += __shfl_xor(ss5, off, 32);
        float al = e5 * __builtin_amdgcn_rcpf(ss5);  // lane (l&31) holds alpha[l&31]
        if (tid < 320) {
            int d = tid;
            float a4[4] = {0.f, 0.f, 0.f, 0.f};
#pragma unroll
            for (int l = 0; l < 32; ++l)
                a4[l & 3] += __shfl(al, l, 32) * (float)scratch[l * 328 + d];
            cbar[ib * 320 + d] = (f16)((a4[0] + a4[1]) + (a4[2] + a4[3]));
        }
    }
}

// ------- out = cbar @ Wo^T + bo, f32 [4096][300]; 256 blocks x M=16 -------
// cA fragments hoisted out of the t-loop (reused across 3 n-tiles).
__global__ __launch_bounds__(512) void out_kernel(
    const f16* __restrict__ cbar, const f16* __restrict__ wo16F,
    const float* __restrict__ bo, float* __restrict__ out) {
    __shared__ __align__(16) f16 cA[16 * 328];
    const int mb = blockIdx.x, tid = threadIdx.x;  // 256 blocks, M=16
    const int w = tid >> 6, lane = tid & 63, lr = lane & 15, quad = lane >> 4;
    for (int i = tid; i < 640; i += 512) {
        int row = i / 40, g = i - row * 40;
        *(half8*)&cA[row * 328 + g * 8] = *(const half8*)&cbar[(mb * 16 + row) * 320 + g * 8];
    }
    __syncthreads();
    const float4v vz = {0.f, 0.f, 0.f, 0.f};
    half8 av[10];
#pragma unroll
    for (int ks = 0; ks < 10; ++ks)
        av[ks] = *(const half8*)&cA[lr * 328 + ks * 32 + quad * 8];
    for (int t = w; t < 19; t += 8) {
        float4v acc = vz;
#pragma unroll
        for (int ks = 0; ks < 10; ++ks) {
            half8 bf = *(const half8*)&wo16F[((t * 10 + ks) * 64 + lane) * 8];
            acc = MFMA16(av[ks], bf, acc);
        }
        int n = t * 16 + lr;
        if (n < 300) {
            float bb = bo[n];
#pragma unroll
            for (int r = 0; r < 4; ++r)
                out[(mb * 16 + quad * 4 + r) * 300 + n] = acc[r] + bb;
        }
    }
}

// ---------------- host launcher ----------------
extern "C" void kernel_launch(void* const* d_in, const int* in_sizes, int n_in,
                              void* d_out, int out_size, void* d_ws, size_t ws_size,
                              hipStream_t stream) {
    const int* title = (const int*)d_in[0];
    const float* emb = (const float*)d_in[1];
    const float* pos = (const float*)d_in[2];
    const float* Wq = (const float*)d_in[3];
    const float* bq = (const float*)d_in[4];
    const float* Wk = (const float*)d_in[5];
    const float* bk = (const float*)d_in[6];
    const float* Wv = (const float*)d_in[7];
    const float* bv = (const float*)d_in[8];
    const float* Wo = (const float*)d_in[9];
    const float* bo = (const float*)d_in[10];
    const float* Va = (const float*)d_in[11];
    const float* ba = (const float*)d_in[12];
    const float* qw = (const float*)d_in[13];
    char* ws = (char*)d_ws;
    float* out = (float*)d_out;

    f16* wqkvF = (f16*)(ws + WQKV_OFF);
    float* bqkv = (float*)(ws + BQKV_OFF);
    f16* wo16F = (f16*)(ws + WO_OFF);
    f16* wvaF = (f16*)(ws + WVA_OFF);
    float* bva = (float*)(ws + BVA_OFF);
    f16* cbar = (f16*)(ws + CBAR_OFF);

    repack_all<<<694, 256, 0, stream>>>(Wq, Wk, Wv, Wo, bq, bk, bv, Va, bo, ba,
                                        wqkvF, wo16F, bqkv, wvaF, bva);
    qkvattn_kernel<<<4096, 512, 0, stream>>>(title, emb, pos, wqkvF, bqkv, wvaF, bva,
                                             qw, cbar);
    out_kernel<<<256, 512, 0, stream>>>(cbar, wo16F, bo, out);
}